// Round 2
// baseline (513.762 us; speedup 1.0000x reference)
//
#include <hip/hip_runtime.h>

// Output layout (all float32, concatenated flat in reference return order):
//   [0, 3V)              : verts_3d  (V,3)  = sigmoid(logit)*2-1 (rows 0..3 = boundary), col2 = 1
//   [3V, 3V+nF)          : faces cast int->float (F,3)
//   [3V+nF, +V*D)        : verts_features pass-through
//
// Round-2 structure change: the 256 MB features pass-through is handed to the
// runtime's tuned blit copy via hipMemcpyAsync (graph-capture-safe per harness
// rules). The rocclr fill dispatches sustain ~6.5 TB/s; our inline copy loop
// measured ~4.6 TB/s effective — let AMD's copy path close that gap.
// The remaining kernel only does the compute parts: verts sigmoid (10 MB) and
// faces int->float cast (24 MB), ~6 us of traffic.

typedef float f32x4 __attribute__((ext_vector_type(4)));
typedef int   i32x4 __attribute__((ext_vector_type(4)));
typedef int   i32x4_u __attribute__((ext_vector_type(4), aligned(4)));

__global__ __launch_bounds__(256) void screen_tri_small(
    const float* __restrict__ logit,
    const float* __restrict__ boundary,
    const int*  __restrict__ faces,
    float* __restrict__ out,
    int V, int nF)
{
    const long long gid = (long long)blockIdx.x * 256 + threadIdx.x;

    float* outV = out;                      // 3V floats
    float* outF = out + (long long)3 * V;   // nF floats

    const long long W1  = (V + 3) >> 2;     // verts groups of 4
    const long long n4f = nF >> 2;          // faces float4 groups

    if (gid < W1) {
        const int base = (int)gid << 2;
        if (gid == 0) {
            // group 0 holds exactly the 4 boundary-pinned rows
            for (int v = 0; v < 4 && v < V; ++v) {
                outV[3 * v + 0] = boundary[2 * v];
                outV[3 * v + 1] = boundary[2 * v + 1];
                outV[3 * v + 2] = 1.0f;
            }
        } else if (base + 4 <= V) {
            // vectorized: 8 floats in (2x float4), 12 floats out (3x float4)
            f32x4 l0 = *(const f32x4*)(logit + 2 * base);
            f32x4 l1 = *(const f32x4*)(logit + 2 * base + 4);
            float xs[4] = { l0.x, l0.z, l1.x, l1.z };
            float ys[4] = { l0.y, l0.w, l1.y, l1.w };
            float o[12] __attribute__((aligned(16)));
            #pragma unroll
            for (int k = 0; k < 4; ++k) {
                o[3 * k + 0] = 2.0f / (1.0f + expf(-xs[k])) - 1.0f;
                o[3 * k + 1] = 2.0f / (1.0f + expf(-ys[k])) - 1.0f;
                o[3 * k + 2] = 1.0f;
            }
            f32x4* dp = (f32x4*)(outV + 3 * base);   // 3*base % 4 == 0 -> 16B aligned
            dp[0] = *(const f32x4*)&o[0];
            dp[1] = *(const f32x4*)&o[4];
            dp[2] = *(const f32x4*)&o[8];
        } else {
            for (int v = base; v < V; ++v) {
                float sx = 2.0f / (1.0f + expf(-logit[2 * v])) - 1.0f;
                float sy = 2.0f / (1.0f + expf(-logit[2 * v + 1])) - 1.0f;
                outV[3 * v + 0] = sx;
                outV[3 * v + 1] = sy;
                outV[3 * v + 2] = 1.0f;
            }
        }
    } else if (gid < W1 + n4f + 1) {
        const long long j = gid - W1;
        if (j < n4f) {
            i32x4 fi = *(const i32x4_u*)(faces + 4 * j);
            f32x4 fo;
            fo.x = (float)fi.x; fo.y = (float)fi.y;
            fo.z = (float)fi.z; fo.w = (float)fi.w;
            *(f32x4*)(outF + 4 * j) = fo;   // 3V % 4 == 0 -> aligned
        } else {
            for (int t = (int)(n4f << 2); t < nF; ++t) outF[t] = (float)faces[t];
        }
    }
}

extern "C" void kernel_launch(void* const* d_in, const int* in_sizes, int n_in,
                              void* d_out, int out_size, void* d_ws, size_t ws_size,
                              hipStream_t stream) {
    const float* verts_logit    = (const float*)d_in[0];
    const float* verts_features = (const float*)d_in[1];
    const float* boundary       = (const float*)d_in[2];
    const int*   faces          = (const int*)d_in[3];

    const int V  = in_sizes[0] / 2;             // 500000
    const int nF = in_sizes[3];                 // F*3 flat elems
    const long long nFeat = (long long)in_sizes[1];  // V*D

    long long W1  = (V + 3) / 4;
    long long n4f = nF / 4;
    long long smallThreads = W1 + n4f + 1;
    int blocksSmall = (int)((smallThreads + 255) / 256);

    // Compute parts (disjoint output ranges from the memcpy; same stream ->
    // serialized, order irrelevant).
    screen_tri_small<<<blocksSmall, 256, 0, stream>>>(
        verts_logit, boundary, faces, (float*)d_out, V, nF);

    // 256 MB features pass-through via the runtime's tuned blit copy.
    float* outX = (float*)d_out + (long long)3 * V + nF;
    hipMemcpyAsync(outX, verts_features, (size_t)nFeat * sizeof(float),
                   hipMemcpyDeviceToDevice, stream);
}

// Round 3
// 455.720 us; speedup vs baseline: 1.1274x; 1.1274x over previous
//
#include <hip/hip_runtime.h>

// Output layout (all float32, concatenated flat in reference return order):
//   [0, 3V)              : verts_3d  (V,3)  = sigmoid(logit)*2-1 (rows 0..3 = boundary), col2 = 1
//   [3V, 3V+nF)          : faces cast int->float (F,3)
//   [3V+nF, +V*D)        : verts_features pass-through
//
// Round-3: revert the hipMemcpyAsync experiment (blit copy measured 2.08 TB/s,
// 44% occupancy — worse than inline). Back to the single fused kernel, but the
// features copy now uses PER-BLOCK CONTIGUOUS CHUNKS instead of grid-stride:
// each block streams one contiguous region sequentially (DRAM page/channel
// locality, the structure the 6.5 TB/s fill kernel uses) with 4 independent
// float4 loads in flight per thread.

typedef float f32x4 __attribute__((ext_vector_type(4)));
typedef int   i32x4 __attribute__((ext_vector_type(4)));
typedef float f32x4_u __attribute__((ext_vector_type(4), aligned(4)));
typedef int   i32x4_u __attribute__((ext_vector_type(4), aligned(4)));

__global__ __launch_bounds__(256) void fused_screen_tri(
    const float* __restrict__ logit,
    const float* __restrict__ feats,
    const float* __restrict__ boundary,
    const int*  __restrict__ faces,
    float* __restrict__ out,
    int V, int nF, long long nFeat)
{
    const long long gid      = (long long)blockIdx.x * 256 + threadIdx.x;
    const long long nthreads = (long long)gridDim.x * 256;

    float* outV = out;                      // 3V floats
    float* outF = out + (long long)3 * V;   // nF floats
    float* outX = outF + nF;                // nFeat floats

    const long long W1  = (V + 3) >> 2;     // verts groups of 4
    const long long n4f = nF >> 2;          // faces float4 groups

    if (gid < W1) {
        const int base = (int)gid << 2;
        if (gid == 0) {
            // group 0 holds exactly the 4 boundary-pinned rows
            for (int v = 0; v < 4 && v < V; ++v) {
                outV[3 * v + 0] = boundary[2 * v];
                outV[3 * v + 1] = boundary[2 * v + 1];
                outV[3 * v + 2] = 1.0f;
            }
        } else if (base + 4 <= V) {
            // vectorized: 8 floats in (2x float4), 12 floats out (3x float4)
            f32x4 l0 = *(const f32x4*)(logit + 2 * base);
            f32x4 l1 = *(const f32x4*)(logit + 2 * base + 4);
            float xs[4] = { l0.x, l0.z, l1.x, l1.z };
            float ys[4] = { l0.y, l0.w, l1.y, l1.w };
            float o[12] __attribute__((aligned(16)));
            #pragma unroll
            for (int k = 0; k < 4; ++k) {
                o[3 * k + 0] = 2.0f / (1.0f + expf(-xs[k])) - 1.0f;
                o[3 * k + 1] = 2.0f / (1.0f + expf(-ys[k])) - 1.0f;
                o[3 * k + 2] = 1.0f;
            }
            f32x4* dp = (f32x4*)(outV + 3 * base);   // 3*base % 4 == 0 -> 16B aligned
            dp[0] = *(const f32x4*)&o[0];
            dp[1] = *(const f32x4*)&o[4];
            dp[2] = *(const f32x4*)&o[8];
        } else {
            for (int v = base; v < V; ++v) {
                float sx = 2.0f / (1.0f + expf(-logit[2 * v])) - 1.0f;
                float sy = 2.0f / (1.0f + expf(-logit[2 * v + 1])) - 1.0f;
                outV[3 * v + 0] = sx;
                outV[3 * v + 1] = sy;
                outV[3 * v + 2] = 1.0f;
            }
        }
    } else if (gid < W1 + n4f + 1) {
        const long long j = gid - W1;
        if (j < n4f) {
            i32x4 fi = *(const i32x4_u*)(faces + 4 * j);
            f32x4 fo;
            fo.x = (float)fi.x; fo.y = (float)fi.y;
            fo.z = (float)fi.z; fo.w = (float)fi.w;
            *(f32x4*)(outF + 4 * j) = fo;   // 3V % 4 == 0 -> aligned
        } else {
            for (int t = (int)(n4f << 2); t < nF; ++t) outF[t] = (float)faces[t];
        }
    }

    // ---- features copy: ALL threads, per-block contiguous chunks ----
    int peel = (int)(((long long)3 * V + nF) & 3);
    peel = (4 - peel) & 3;                       // scalar head so dst is 16B-aligned
    if (peel > nFeat) peel = (int)nFeat;
    if (gid < peel) outX[gid] = feats[gid];

    const float* s = feats + peel;               // may be only 4B-aligned
    float*       d = outX + peel;                // 16B-aligned by construction
    const long long m  = nFeat - peel;
    const long long m4 = m >> 2;                 // float4 groups

    // Each block owns one contiguous run of float4 groups and streams it
    // sequentially: per iteration a block covers 256*16B = 4 KB contiguous.
    const long long chunk = (m4 + gridDim.x - 1) / gridDim.x;
    const long long beg   = (long long)blockIdx.x * chunk;
    long long       end   = beg + chunk;
    if (end > m4) end = m4;

    long long i = beg + threadIdx.x;
    // 4 independent loads in flight before any store (MLP).
    for (; i + 768 < end; i += 1024) {
        f32x4 v0 = *(const f32x4_u*)(s + 4 * i);
        f32x4 v1 = *(const f32x4_u*)(s + 4 * (i + 256));
        f32x4 v2 = *(const f32x4_u*)(s + 4 * (i + 512));
        f32x4 v3 = *(const f32x4_u*)(s + 4 * (i + 768));
        *(f32x4*)(d + 4 * i)         = v0;
        *(f32x4*)(d + 4 * (i + 256)) = v1;
        *(f32x4*)(d + 4 * (i + 512)) = v2;
        *(f32x4*)(d + 4 * (i + 768)) = v3;
    }
    for (; i < end; i += 256) {
        f32x4 v = *(const f32x4_u*)(s + 4 * i);
        *(f32x4*)(d + 4 * i) = v;
    }
    // scalar tail (m % 4 floats)
    for (long long t = (m4 << 2) + gid; t < m; t += nthreads) d[t] = s[t];
}

extern "C" void kernel_launch(void* const* d_in, const int* in_sizes, int n_in,
                              void* d_out, int out_size, void* d_ws, size_t ws_size,
                              hipStream_t stream) {
    const float* verts_logit    = (const float*)d_in[0];
    const float* verts_features = (const float*)d_in[1];
    const float* boundary       = (const float*)d_in[2];
    const int*   faces          = (const int*)d_in[3];

    const int V  = in_sizes[0] / 2;             // 500000
    const int nF = in_sizes[3];                 // F*3 flat elems
    const long long nFeat = (long long)in_sizes[1];  // V*D

    long long W1  = (V + 3) / 4;
    long long n4f = nF / 4;
    long long smallThreads = W1 + n4f + 1;
    int blocksSmall = (int)((smallThreads + 255) / 256);

    // 2048 blocks = 8 per CU (G11 memory-bound default). Each block's chunk is
    // ~16M/2048 = 8192 float4 groups = 128 KB contiguous.
    int blocks = 2048;
    if (blocksSmall > blocks) blocks = blocksSmall;

    fused_screen_tri<<<blocks, 256, 0, stream>>>(
        verts_logit, verts_features, boundary, faces,
        (float*)d_out, V, nF, nFeat);
}